// Round 8
// baseline (340.056 us; speedup 1.0000x reference)
//
#include <hip/hip_runtime.h>
#include <math.h>

#define WIN 11
#define PAD 5

typedef float v2f __attribute__((ext_vector_type(2)));

struct GW { float g[WIN]; };

// ---------------------------------------------------------------------------
// Wave-autonomous SSIM tile, DOUBLE-ROW STATIC-RING edition, TEMPLATE steps.
// R7 post-mortem: identical structure expressed via _Pragma-in-macro left the
// ring loops UNROLLED-NOT -> runtime indices -> vM/vS lowered to scratch
// (WRITE_SIZE 200MB, VGPR 64, dur +65%). This version delivers the same
// schedule through template<int U> step functions: every ring index and tap
// weight is a compile-time constant under a real #pragma unroll.
// Structure (one step = image rows 2d, 2d+1):
//   - branchless depth-1-step (2-row) prefetch (R5: uniform vmcnt)
//   - LDS float4 (p0,q0,p1,q1): 11 ds_read_b128 + 2 writes per 2 rows
//     (halves DS instruction count vs float2-per-row; R7 measured bank
//     conflicts halved too)
//   - packed H-conv of both rows per tap (6 pk-ops) = same VALU/row as R5
//   - packed V-conv ring vM[s]=(Mp,Mq), vS[s]=(Sp,Sq): 44 pk_fma per 2 rows
//     (halves R5's 88 scalar). STATIC 12-slot ring: slot s holds output
//     o == s (mod 12); step d: row 2d taps w0=(2d-s)%12 (if <=10), row 2d+1
//     taps w1=w0+1 (if <=10); slots (2d+2)%12,(2d+3)%12 emit outputs
//     2d-10, 2d-9 then zero. Startup transient slots accumulate garbage and
//     are zeroed before first real tap (R7 verified absmax 0.0).
//   - 21 steps = rows 0..41 exactly: 3x unrolled blocks of 6 + 3-step tail,
//     U = d mod 6 a template literal at every call site.
// R0-R7 meta: duration tracks per-row VALU + DS instruction counts; latency
// tricks alone are null. This cuts VALU ~45% and DS ~50% per row vs R5.
// Tripwire: WRITE_SIZE must be ~24.8MB / FETCH ~78MB; growth = spill.
// EMIT: L0 pools rows (2d-1, 2d) into L1 at steps with 6 <= 2d <= 36.
// ---------------------------------------------------------------------------

struct TileCtx {
    const float* p1; const float* p2;
    float* o1a; float* o1b;
    int W, X0, Y0, Wout;
    int lane, cpos, wpos, gxc, hxc;
    bool cval, hval;
};

__device__ __forceinline__ void load_row(const TileCtx& c, int t,
    float& oa, float& ob, float& oah, float& obh)
{
    int y = c.Y0 - PAD + t;
    bool yin = (unsigned)y < (unsigned)c.W;
    const float* r1 = c.p1 + (size_t)(yin ? y : 0) * c.W;
    const float* r2 = c.p2 + (size_t)(yin ? y : 0) * c.W;
    float va = r1[c.gxc], vb = r2[c.gxc];
    float wa = r1[c.hxc], wb = r2[c.hxc];
    bool cv = yin && c.cval;
    bool hv = yin && c.hval;
    oa  = cv ? va : 0.f;
    ob  = cv ? vb : 0.f;
    oah = hv ? wa : 0.f;
    obh = hv ? wb : 0.f;
}

__device__ __forceinline__ void emit_one(const TileCtx& cx, v2f M, v2f S,
                                         int o, float& part)
{
    const int TH = 32;
    if ((unsigned)o < (unsigned)TH) {
        bool yok = (unsigned)(cx.Y0 + o) < (unsigned)cx.W;   // false only for L4 tail
        float Mp = M.x, Mq = M.y, Sp_ = S.x, Sq_ = S.y;
        const float C1v = 1e-4f, C2v = 9e-4f;
        float A = Mp * Mp, B = Mq * Mq;
        float ABp = A + B, ABm = A - B;
        float SSp = Sp_ + Sq_, SSm = Sp_ - Sq_;
        float n1 = fmaf(0.5f, ABm, C1v);         // 2*m12 + C1
        float n2 = fmaf(0.5f, SSm - ABm, C2v);   // 2*s12 + C2
        float e1 = fmaf(0.5f, ABp, C1v);         // m1^2+m2^2 + C1
        float e2 = fmaf(0.5f, SSp - ABp, C2v);   // s1+s2 + C2
        float val = (n1 * n2) * __builtin_amdgcn_rcpf(e1 * e2);
        part += (cx.cval && yok) ? val : 0.f;
    }
}

template<int U, bool EMIT>
__device__ __forceinline__ void ssim_step(
    const TileCtx& cx, const GW& gw, float4* __restrict__ rb, int d,
    float (&cur)[8], v2f (&vM)[12], v2f (&vS)[12],
    float& part, float& pprev, float& qprev)
{
    // 1) prefetch next double-row (rows 2d+2, 2d+3), consumed next step
    float n0, n1, n2, n3, n4, n5, n6, n7;
    load_row(cx, 2 * d + 2, n0, n1, n2, n3);
    load_row(cx, 2 * d + 3, n4, n5, n6, n7);

    // 2) LDS write rows (2d, 2d+1) packed as float4
    float p0  = cur[0] + cur[1], q0  = cur[0] - cur[1];
    float ph0 = cur[2] + cur[3], qh0 = cur[2] - cur[3];
    float p1r = cur[4] + cur[5], q1r = cur[4] - cur[5];
    float ph1 = cur[6] + cur[7], qh1 = cur[6] - cur[7];
    rb[cx.cpos] = make_float4(p0, q0, p1r, q1r);
    rb[cx.wpos] = (cx.lane < 10) ? make_float4(ph0, qh0, ph1, qh1)
                                 : make_float4(p0, q0, p1r, q1r);
    __builtin_amdgcn_wave_barrier();   // writes -> reads (cross-lane RAW)

    // 3) H-conv of both rows from one b128 read per tap
    v2f hM0 = {0.f, 0.f}, hS0 = {0.f, 0.f};
    v2f hM1 = {0.f, 0.f}, hS1 = {0.f, 0.f};
#pragma unroll
    for (int j = 0; j < WIN; ++j) {
        float4 vv = rb[cx.lane + j];
        v2f v0 = { vv.x, vv.y }, v1 = { vv.z, vv.w };
        v2f g2 = { gw.g[j], gw.g[j] };
        hM0 = __builtin_elementwise_fma(g2, v0, hM0);
        hS0 = __builtin_elementwise_fma(g2, v0 * v0, hS0);
        hM1 = __builtin_elementwise_fma(g2, v1, hM1);
        hS1 = __builtin_elementwise_fma(g2, v1 * v1, hS1);
    }
    __builtin_amdgcn_wave_barrier();   // reads -> next step's writes (WAR)

    // 4) V-conv static ring, packed accumulators; weights fold at compile time
#pragma unroll
    for (int s = 0; s < 12; ++s) {
        const int w0v = ((2 * U - s) % 12 + 12) % 12;
        if (w0v <= 10) {
            v2f g2 = { gw.g[w0v], gw.g[w0v] };
            vM[s] = __builtin_elementwise_fma(g2, hM0, vM[s]);
            vS[s] = __builtin_elementwise_fma(g2, hS0, vS[s]);
        }
        const int w1v = (w0v + 1) % 12;
        if (w1v <= 10) {
            v2f g2 = { gw.g[w1v], gw.g[w1v] };
            vM[s] = __builtin_elementwise_fma(g2, hM1, vM[s]);
            vS[s] = __builtin_elementwise_fma(g2, hS1, vS[s]);
        }
    }

    // 5) emit the two completed outputs (o = 2d-10, 2d-9), zero their slots
    {
        const int s0 = (2 * U + 2) % 12;
        const int s1 = (2 * U + 3) % 12;
        emit_one(cx, vM[s0], vS[s0], 2 * d - 10, part);
        emit_one(cx, vM[s1], vS[s1], 2 * d - 9,  part);
        vM[s0] = (v2f){0.f, 0.f}; vS[s0] = (v2f){0.f, 0.f};
        vM[s1] = (v2f){0.f, 0.f}; vS[s1] = (v2f){0.f, 0.f};
    }

    // 6) L0 pooling of image rows (2d-1, 2d) -> L1
    if (EMIT) {
        int r_ = 2 * d;
        if (r_ >= 6 && r_ <= 36) {
            float sp_ = p0 + pprev, sq_ = q0 + qprev;
            float sp2 = sp_ + __shfl_down(sp_, 1, 64);
            float sq2 = sq_ + __shfl_down(sq_, 1, 64);
            if ((cx.lane & 1) == 0) {
                float P = sp2 * 0.25f, Q = sq2 * 0.25f;
                int yo = d - 3;
                size_t oo = (size_t)((cx.Y0 >> 1) + yo) * cx.Wout
                          + ((cx.X0 >> 1) + (cx.lane >> 1));
                cx.o1a[oo] = (P + Q) * 0.5f;
                cx.o1b[oo] = (P - Q) * 0.5f;
            }
        }
        pprev = p1r; qprev = q1r;
    }

    // 7) rotate prefetch regs (static indices)
    cur[0] = n0; cur[1] = n1; cur[2] = n2; cur[3] = n3;
    cur[4] = n4; cur[5] = n5; cur[6] = n6; cur[7] = n7;

    // pin step boundary: no cross-step motion (R8 unroll-hoist trap)
    __builtin_amdgcn_sched_barrier(0);
}

template<bool EMIT>
__device__ __forceinline__ float ssim_wave_tile(
    const float* __restrict__ p1, const float* __restrict__ p2,
    int W, int X0, int Y0, const GW& gw, float4* __restrict__ rb,
    float* __restrict__ o1a, float* __restrict__ o1b, int Wout)
{
    TileCtx cx;
    cx.p1 = p1; cx.p2 = p2; cx.o1a = o1a; cx.o1b = o1b;
    cx.W = W; cx.X0 = X0; cx.Y0 = Y0; cx.Wout = Wout;
    cx.lane = threadIdx.x & 63;
    const int gx = X0 + cx.lane;
    cx.cval = gx < W;                                      // false only for L4 lanes 32+
    const int hx = (cx.lane < 5) ? (X0 - 5 + cx.lane) : (X0 + 59 + cx.lane);
    cx.hval = (cx.lane < 10) && ((unsigned)hx < (unsigned)W);
    const int hpos = (cx.lane < 5) ? cx.lane : (64 + cx.lane);  // 0..4 | 69..73
    cx.cpos = 5 + cx.lane;
    cx.gxc = cx.cval ? gx : 0;
    cx.hxc = cx.hval ? hx : cx.gxc;                        // masked halo -> own col
    cx.wpos = (cx.lane < 10) ? hpos : cx.cpos;             // branchless halo write

    v2f vM[12], vS[12];
#pragma unroll
    for (int k = 0; k < 12; ++k) { vM[k] = (v2f){0.f, 0.f}; vS[k] = (v2f){0.f, 0.f}; }

    float part = 0.f, pprev = 0.f, qprev = 0.f;
    float cur[8];
    load_row(cx, 0, cur[0], cur[1], cur[2], cur[3]);
    load_row(cx, 1, cur[4], cur[5], cur[6], cur[7]);

    // 21 double-steps (rows 0..41): 3 unrolled blocks of 6 + 3-step tail.
#pragma unroll 1
    for (int blk = 0; blk < 3; ++blk) {
        const int db = blk * 6;
        ssim_step<0, EMIT>(cx, gw, rb, db + 0, cur, vM, vS, part, pprev, qprev);
        ssim_step<1, EMIT>(cx, gw, rb, db + 1, cur, vM, vS, part, pprev, qprev);
        ssim_step<2, EMIT>(cx, gw, rb, db + 2, cur, vM, vS, part, pprev, qprev);
        ssim_step<3, EMIT>(cx, gw, rb, db + 3, cur, vM, vS, part, pprev, qprev);
        ssim_step<4, EMIT>(cx, gw, rb, db + 4, cur, vM, vS, part, pprev, qprev);
        ssim_step<5, EMIT>(cx, gw, rb, db + 5, cur, vM, vS, part, pprev, qprev);
    }
    ssim_step<0, EMIT>(cx, gw, rb, 18, cur, vM, vS, part, pprev, qprev);
    ssim_step<1, EMIT>(cx, gw, rb, 19, cur, vM, vS, part, pprev, qprev);
    ssim_step<2, EMIT>(cx, gw, rb, 20, cur, vM, vS, part, pprev, qprev);

    return part;
}

// ---- L0: 8x16 tiles (64x32) x 48 images = 6144 waves (1536 blocks); emits L1 ----
__global__ __launch_bounds__(256, 4) void ssim_l0_kernel(
    const float* __restrict__ i1, const float* __restrict__ i2,
    float* __restrict__ a1, float* __restrict__ b1,
    double* __restrict__ acc, GW gw)
{
    __shared__ float4 rbs[4][80];
    const int wid = threadIdx.x >> 6;
    const int w = blockIdx.x * 4 + wid;
    const int img = w >> 7;                 // 128 tiles per image
    const int tt = w & 127;
    const int tx = tt & 7, ty = tt >> 3;    // 8 cols x 16 rows
    const size_t off  = (size_t)img * 512 * 512;
    const size_t ooff = (size_t)img * 256 * 256;

    float part = ssim_wave_tile<true>(i1 + off, i2 + off, 512, tx * 64, ty * 32,
                                      gw, rbs[wid], a1 + ooff, b1 + ooff, 256);
#pragma unroll
    for (int o = 32; o > 0; o >>= 1) part += __shfl_down(part, o, 64);
    if ((threadIdx.x & 63) == 0) atomicAdd(acc, (double)part);
}

// ---- L1..L4, all 64x32 tiles: 32+8+2+1 = 43 tiles/image = 2064 waves (516 blocks) ----
__global__ __launch_bounds__(256, 4) void ssim_rest_kernel(
    const float* __restrict__ a1, const float* __restrict__ b1,
    const float* __restrict__ a2, const float* __restrict__ b2,
    const float* __restrict__ a3, const float* __restrict__ b3,
    const float* __restrict__ a4, const float* __restrict__ b4,
    double* __restrict__ acc, GW gw)
{
    __shared__ float4 rbs[4][80];
    const int wid = threadIdx.x >> 6;
    const int w = blockIdx.x * 4 + wid;
    const int img = w / 43;
    const int r = w - img * 43;
    int lvl, tx, ty;
    if (r < 32)      { lvl = 1; tx = r & 3;  ty = r >> 2; }                // 4x8
    else if (r < 40) { lvl = 2; int s = r - 32; tx = s & 1; ty = s >> 1; } // 2x4
    else if (r < 42) { lvl = 3; tx = 0; ty = r - 40; }                     // 1x2
    else             { lvl = 4; tx = 0; ty = 0; }                          // 1x1
    const int W = 512 >> lvl;
    const float* p1; const float* p2;
    switch (lvl) {
      case 1:  p1 = a1; p2 = b1; break;
      case 2:  p1 = a2; p2 = b2; break;
      case 3:  p1 = a3; p2 = b3; break;
      default: p1 = a4; p2 = b4; break;
    }
    const size_t off = (size_t)img * W * W;

    float part = ssim_wave_tile<false>(p1 + off, p2 + off, W, tx * 64, ty * 32,
                                       gw, rbs[wid], nullptr, nullptr, 0);
#pragma unroll
    for (int o = 32; o > 0; o >>= 1) part += __shfl_down(part, o, 64);
    if ((threadIdx.x & 63) == 0) atomicAdd(acc + lvl, (double)part);
}

// ---- pool L1 -> L2/L3/L4. Grid (16, 96). ----
__global__ __launch_bounds__(256) void pool_rest_kernel(
    const float* __restrict__ a1, const float* __restrict__ b1,
    float* __restrict__ a2, float* __restrict__ b2,
    float* __restrict__ a3, float* __restrict__ b3,
    float* __restrict__ a4, float* __restrict__ b4)
{
    __shared__ float l2[32][33];
    __shared__ float l3[16][17];
    const int tid = threadIdx.x;
    const int im = blockIdx.y;
    const int tb = blockIdx.x;
    const int tx = tb & 3, ty = tb >> 2;
    const bool second = im >= 48;
    const int ii = second ? im - 48 : im;
    const float* src = (second ? b1 : a1) + (size_t)ii * 256 * 256;
    float* o2 = (second ? b2 : a2) + (size_t)ii * 128 * 128;
    float* o3 = (second ? b3 : a3) + (size_t)ii * 64 * 64;
    float* o4 = (second ? b4 : a4) + (size_t)ii * 32 * 32;
    const int X0 = tx * 64, Y0 = ty * 64;

#pragma unroll
    for (int k = 0; k < 2; ++k) {
        int idx = tid + k * 256;
        int xp = idx & 15;
        int yo = idx >> 4;
        const float* rp = src + (size_t)(Y0 + 2 * yo) * 256 + (X0 + 4 * xp);
        float4 r0 = *(const float4*)rp;
        float4 r1 = *(const float4*)(rp + 256);
        float v0 = (r0.x + r0.y + r1.x + r1.y) * 0.25f;
        float v1 = (r0.z + r0.w + r1.z + r1.w) * 0.25f;
        l2[yo][2 * xp]     = v0;
        l2[yo][2 * xp + 1] = v1;
        float2* op = (float2*)(o2 + (size_t)((Y0 >> 1) + yo) * 128 + ((X0 >> 1) + 2 * xp));
        *op = make_float2(v0, v1);
    }
    __syncthreads();
    {
        int xo = tid & 15, yo = tid >> 4;
        if (yo < 16) {
            float v = (l2[2*yo][2*xo] + l2[2*yo][2*xo+1] +
                       l2[2*yo+1][2*xo] + l2[2*yo+1][2*xo+1]) * 0.25f;
            l3[yo][xo] = v;
            o3[(size_t)((Y0 >> 2) + yo) * 64 + ((X0 >> 2) + xo)] = v;
        }
    }
    __syncthreads();
    if (tid < 64) {
        int xo = tid & 7, yo = tid >> 3;
        float v = (l3[2*yo][2*xo] + l3[2*yo][2*xo+1] +
                   l3[2*yo+1][2*xo] + l3[2*yo+1][2*xo+1]) * 0.25f;
        o4[(size_t)((Y0 >> 3) + yo) * 32 + ((X0 >> 3) + xo)] = v;
    }
}

__global__ void final_kernel(const double* __restrict__ acc, float* __restrict__ out)
{
    double loss = 0.0;
#pragma unroll
    for (int l = 0; l < 5; ++l) {
        double cnt = 48.0 * (double)(512 >> l) * (double)(512 >> l);
        loss += 1.0 - acc[l] / cnt;
    }
    out[0] = (float)loss;
}

extern "C" void kernel_launch(void* const* d_in, const int* in_sizes, int n_in,
                              void* d_out, int out_size, void* d_ws, size_t ws_size,
                              hipStream_t stream)
{
    const float* img1 = (const float*)d_in[0];
    const float* img2 = (const float*)d_in[1];
    float* out = (float*)d_out;

    // 1D gaussian (sigma=1.5, k=11), matches reference construction
    GW gw;
    double gs[WIN], sum = 0.0;
    for (int i = 0; i < WIN; ++i) {
        double ax = (double)i - 5.0;
        gs[i] = exp(-(ax * ax) / 4.5);
        sum += gs[i];
    }
    for (int i = 0; i < WIN; ++i) gw.g[i] = (float)(gs[i] / sum);

    // workspace: 64B header (5 double acc), then pyramid
    double* acc = (double*)d_ws;
    float* base = (float*)((char*)d_ws + 64);
    const size_t n1 = 48ull * 256 * 256;
    const size_t n2 = 48ull * 128 * 128;
    const size_t n3 = 48ull * 64 * 64;
    const size_t n4 = 48ull * 32 * 32;
    float* a1 = base;      float* b1 = a1 + n1;
    float* a2 = b1 + n1;   float* b2 = a2 + n2;
    float* a3 = b2 + n2;   float* b3 = a3 + n3;
    float* a4 = b3 + n3;   float* b4 = a4 + n4;

    hipMemsetAsync(acc, 0, 5 * sizeof(double), stream);

    hipLaunchKernelGGL(ssim_l0_kernel, dim3(1536), dim3(256), 0, stream,
                       img1, img2, a1, b1, acc, gw);

    hipLaunchKernelGGL(pool_rest_kernel, dim3(16, 96), dim3(256), 0, stream,
                       a1, b1, a2, b2, a3, b3, a4, b4);

    hipLaunchKernelGGL(ssim_rest_kernel, dim3(516), dim3(256), 0, stream,
                       a1, b1, a2, b2, a3, b3, a4, b4, acc, gw);

    hipLaunchKernelGGL(final_kernel, dim3(1), dim3(1), 0, stream, acc, out);
}